// Round 6
// baseline (141.608 us; speedup 1.0000x reference)
//
#include <hip/hip_runtime.h>
#include <hip/hip_bf16.h>
#include <math.h>

#define B_ 8
#define C_ 256
#define H_ 31
#define W_ 31
#define T_ 7
#define K_ 49
#define OC_ 147
#define OCP 160
#define OH_ 25
#define OW_ 25
#define NSP 961   // 31*31
#define OSP 625   // 25*25
#define KK_ 2304  // 256*9

typedef __bf16 bf16x8 __attribute__((ext_vector_type(8)));
typedef float f32x4 __attribute__((ext_vector_type(4)));

// workspace layout (byte offsets, all 16B aligned)
#define OFFB_SRT 0                      // 3,936,256  srT bf16 [b][s][c]
#define OFFB_TMT 3936256                // 200,704    tmT bf16 [b][k][c]
#define OFFB_WPK 4136960                // 737,280    wPk bf16 fragment-order (9-shift)
#define OFFB_BIAS 4874240               // 640        biasP f32 [160]
#define OFFB_OM  4874880                // 12,800,000 om f32 [b][i][cg][j=25][oc=160]

__device__ inline float blo(unsigned u) { return __uint_as_float(u << 16); }
__device__ inline float bhi(unsigned u) { return __uint_as_float(u & 0xffff0000u); }

// ---------------- PREP: fused k1 (srT) + k2 (tmT) + k2b (wPk, biasP) ------
// blocks 0..1983: sr transpose; 1984..2375: tmpl transpose; 2376..2555: w pack
__global__ __launch_bounds__(256) void prep(const float* __restrict__ sr,
                                            const float* __restrict__ tm,
                                            const float* __restrict__ w,
                                            const float* __restrict__ bias,
                                            __hip_bfloat16* __restrict__ srT,
                                            __hip_bfloat16* __restrict__ tmT,
                                            __hip_bfloat16* __restrict__ wPk,
                                            float* __restrict__ biasP) {
    __shared__ float tile[32][33];
    int bid = blockIdx.x;
    int t = threadIdx.x;

    if (bid < 1984) {
        // ---- k1: sr (NCHW fp32) -> srT[b][s][c] bf16
        int b = bid / 248;
        int rem = bid % 248;
        int ct = rem / 31;
        int st = rem % 31;
        int c0 = ct * 32, s0 = st * 32;
        int tx = t & 31, ty = t >> 5;
        #pragma unroll
        for (int rr = 0; rr < 4; rr++) {
            int c = c0 + ty + rr * 8;
            int s = s0 + tx;
            if (s < NSP) tile[ty + rr * 8][tx] = sr[(b * C_ + c) * NSP + s];
        }
        __syncthreads();
        #pragma unroll
        for (int rr = 0; rr < 4; rr++) {
            int s = s0 + ty + rr * 8;
            int c = c0 + tx;
            if (s < NSP) srT[((long)b * NSP + s) * C_ + c] = __float2bfloat16(tile[tx][ty + rr * 8]);
        }
    } else if (bid < 2376) {
        // ---- k2: tmpl[b][c][k] -> tmplT[b][k][c] bf16
        int bx = bid - 1984;
        int b = bx / K_;
        int k = bx % K_;
        tmT[(b * K_ + k) * C_ + t] = __float2bfloat16(tm[(b * C_ + t) * K_ + k]);
    } else {
        // ---- k2b: w -> wPk 9-shift fragment order; bias pad
        if (bid == 2376 && t < OCP)
            biasP[t] = (t < OC_) ? bias[t] : 0.f;
        int i = (bid - 2376) * 256 + t;   // 46080 total
        if (i < 46080) {
            int l = i & 63;
            int fid = i >> 6;             // 0..719
            int mf = fid % 5;
            int mh = (fid / 5) % 2;
            int ks = (fid / 10) % 2;
            int s  = (fid / 20) % 9;
            int cg = fid / 180;
            int oc = mh * 80 + mf * 16 + (l & 15);
            int cbase = cg * 64 + ks * 32 + (l >> 4) * 8;
            bf16x8 v;
            #pragma unroll
            for (int jj = 0; jj < 8; jj++) {
                float f = (oc < OC_) ? w[oc * KK_ + (cbase + jj) * 9 + s] : 0.f;
                v[jj] = (__bf16)f;
            }
            *reinterpret_cast<bf16x8*>(wPk + ((long)i << 3)) = v;
        }
    }
}

// ---------------- K3: conv via 9-shift bf16 MFMA GEMM ---------------------
// block = (b, out-row i, channel-group cg); 128 threads = 2 waves (mh 0/1).
// LDS: raw sr slab rows y=i-1..i+1, xi=0..26, 64 ch; row stride 72 bf16 (144B).
// om layout: [b][i][cg][j=25][oc=160] fp32
__global__ __launch_bounds__(128) void k3_mfma(const __hip_bfloat16* __restrict__ srT,
                                               const __hip_bfloat16* __restrict__ wPk,
                                               float* __restrict__ om) {
    __shared__ __hip_bfloat16 lds[88 * 72];   // 81 real rows + margin for j>=25 lanes
    int sb = (blockIdx.x & 7) * 100 + (blockIdx.x >> 3);  // XCD-chunked
    int b = sb / 100;
    int rem = sb % 100;
    int i = rem / 4;
    int cg = rem % 4;
    int tid = threadIdx.x;

    const __hip_bfloat16* srTb = srT + (long)b * NSP * C_ + cg * 64;
    for (int o = tid; o < 648; o += 128) {
        int ryx = o >> 3;
        int c8 = (o & 7) * 8;
        int yy = ryx / 27;
        int xi = ryx - yy * 27;
        int y = i - 1 + yy;
        int x = xi - 1;
        bf16x8 v = {};
        if (y >= 0 && x >= 0)
            v = *reinterpret_cast<const bf16x8*>(srTb + (y * W_ + x) * C_ + c8);
        *reinterpret_cast<bf16x8*>(&lds[ryx * 72 + c8]) = v;
    }
    __syncthreads();

    int wv = tid >> 6;        // mh
    int l = tid & 63;
    int lr = l & 15, lg = l >> 4;

    f32x4 acc[5][2] = {};
    const bf16x8* apk = reinterpret_cast<const bf16x8*>(wPk);

    #pragma unroll
    for (int dy = 0; dy < 3; ++dy) {
        #pragma unroll
        for (int dx = 0; dx < 3; ++dx) {
            int s = dy * 3 + dx;
            #pragma unroll
            for (int ks = 0; ks < 2; ++ks) {
                int e0 = (dy * 27 + dx + lr) * 72 + ks * 32 + lg * 8;
                bf16x8 b0 = *reinterpret_cast<const bf16x8*>(&lds[e0]);
                bf16x8 b1 = *reinterpret_cast<const bf16x8*>(&lds[e0 + 16 * 72]);
                const bf16x8* ap = apk + (long)((((cg * 9 + s) * 2 + ks) * 2 + wv) * 5) * 64 + l;
                #pragma unroll
                for (int mf = 0; mf < 5; ++mf) {
                    bf16x8 a = ap[mf * 64];
                    acc[mf][0] = __builtin_amdgcn_mfma_f32_16x16x32_bf16(a, b0, acc[mf][0], 0, 0, 0);
                    acc[mf][1] = __builtin_amdgcn_mfma_f32_16x16x32_bf16(a, b1, acc[mf][1], 0, 0, 0);
                }
            }
        }
    }

    #pragma unroll
    for (int nf = 0; nf < 2; ++nf) {
        int j = nf * 16 + lr;
        if (j < OW_) {
            float* ob = om + (long)((b * OH_ + i) * 4 + cg) * (OW_ * OCP) + j * OCP + wv * 80 + lg * 4;
            #pragma unroll
            for (int mf = 0; mf < 5; ++mf)
                *reinterpret_cast<f32x4*>(ob + mf * 16) = acc[mf][nf];
        }
    }
}

// ---------------- K4: offsets/mask + bilinear gather + reduce -------------
// block = (b,i,j); 128 threads = 2 waves; k-range split across waves;
// each lane handles 4 channels (dwordx2 = 8B/lane, full 512B row per wave).
__global__ __launch_bounds__(128) void k4_gather(const __hip_bfloat16* __restrict__ srT,
                                                 const __hip_bfloat16* __restrict__ tmT,
                                                 const float* __restrict__ om,
                                                 const float* __restrict__ biasP,
                                                 float* __restrict__ out) {
    __shared__ float lom[OCP];
    __shared__ int4 loff[K_];      // BYTE row offsets
    __shared__ float4 lwt[K_];
    __shared__ float red[64][4];
    int sb = (blockIdx.x & 7) * 625 + (blockIdx.x >> 3);  // XCD = batch
    int b = sb / OSP;
    int rem = sb % OSP;
    int i = rem / OW_;
    int j = rem % OW_;
    int t = threadIdx.x;

    if (t < 40) {
        f32x4 s = *reinterpret_cast<const f32x4*>(biasP + t * 4);
        const float* ob = om + (long)(b * OH_ + i) * (4 * OW_ * OCP) + j * OCP + t * 4;
        #pragma unroll
        for (int cg = 0; cg < 4; cg++)
            s += *reinterpret_cast<const f32x4*>(ob + cg * (OW_ * OCP));
        *reinterpret_cast<f32x4*>(lom + t * 4) = s;
    }
    __syncthreads();

    if (t < K_) {
        float oy = lom[t];
        float ox = lom[K_ + t];
        float mk = 1.f / (1.f + expf(-lom[2 * K_ + t]));
        float ys = (float)(i + t / T_) + oy;
        float xs = (float)(j + t % T_) + ox;
        float y0f = floorf(ys);
        float x0f = floorf(xs);
        float wy = ys - y0f, wx = xs - x0f;
        bool vy0 = (y0f >= 0.f) && (y0f <= 30.f);
        bool vy1 = (y0f >= -1.f) && (y0f <= 29.f);
        bool vx0 = (x0f >= 0.f) && (x0f <= 30.f);
        bool vx1 = (x0f >= -1.f) && (x0f <= 29.f);
        int iy = (int)y0f;
        int ix = (int)x0f;
        int cy0 = min(max(iy, 0), 30), cy1 = min(max(iy + 1, 0), 30);
        int cx0 = min(max(ix, 0), 30), cx1 = min(max(ix + 1, 0), 30);
        float a00 = (1.f - wy) * (1.f - wx), a01 = (1.f - wy) * wx;
        float a10 = wy * (1.f - wx), a11 = wy * wx;
        lwt[t] = make_float4(mk * a00 * (float)(vy0 && vx0),
                             mk * a01 * (float)(vy0 && vx1),
                             mk * a10 * (float)(vy1 && vx0),
                             mk * a11 * (float)(vy1 && vx1));
        loff[t] = make_int4((cy0 * W_ + cx0) * 512, (cy0 * W_ + cx1) * 512,
                            (cy1 * W_ + cx0) * 512, (cy1 * W_ + cx1) * 512);
    }
    __syncthreads();

    int wv = t >> 6, lane = t & 63;
    const char* srBase = (const char*)srT + (long)b * NSP * 512;
    const char* tmBase = (const char*)tmT + (long)b * K_ * 512;
    unsigned laneb = lane << 3;
    float a0 = 0.f, a1 = 0.f, a2 = 0.f, a3 = 0.f;
    int kb = wv ? 25 : 0, ke = wv ? 49 : 25;

    for (int k = kb; k < ke; ++k) {
        int4 o = loff[k];
        float4 wt = lwt[k];
        uint2 u00 = *reinterpret_cast<const uint2*>(srBase + (unsigned)o.x + laneb);
        uint2 u01 = *reinterpret_cast<const uint2*>(srBase + (unsigned)o.y + laneb);
        uint2 u10 = *reinterpret_cast<const uint2*>(srBase + (unsigned)o.z + laneb);
        uint2 u11 = *reinterpret_cast<const uint2*>(srBase + (unsigned)o.w + laneb);
        uint2 tu  = *reinterpret_cast<const uint2*>(tmBase + ((unsigned)k << 9) + laneb);
        float s;
        s = wt.x * blo(u00.x); s = fmaf(wt.y, blo(u01.x), s);
        s = fmaf(wt.z, blo(u10.x), s); s = fmaf(wt.w, blo(u11.x), s);
        a0 = fmaf(blo(tu.x), s, a0);
        s = wt.x * bhi(u00.x); s = fmaf(wt.y, bhi(u01.x), s);
        s = fmaf(wt.z, bhi(u10.x), s); s = fmaf(wt.w, bhi(u11.x), s);
        a1 = fmaf(bhi(tu.x), s, a1);
        s = wt.x * blo(u00.y); s = fmaf(wt.y, blo(u01.y), s);
        s = fmaf(wt.z, blo(u10.y), s); s = fmaf(wt.w, blo(u11.y), s);
        a2 = fmaf(blo(tu.y), s, a2);
        s = wt.x * bhi(u00.y); s = fmaf(wt.y, bhi(u01.y), s);
        s = fmaf(wt.z, bhi(u10.y), s); s = fmaf(wt.w, bhi(u11.y), s);
        a3 = fmaf(bhi(tu.y), s, a3);
    }

    if (wv) {
        red[lane][0] = a0; red[lane][1] = a1;
        red[lane][2] = a2; red[lane][3] = a3;
    }
    __syncthreads();
    if (!wv) {
        a0 += red[lane][0]; a1 += red[lane][1];
        a2 += red[lane][2]; a3 += red[lane][3];
        long ob = ((long)(b * C_ + 4 * lane) * OH_ + i) * OW_ + j;
        out[ob] = a0;
        out[ob + OSP] = a1;
        out[ob + 2 * OSP] = a2;
        out[ob + 3 * OSP] = a3;
    }
}

extern "C" void kernel_launch(void* const* d_in, const int* in_sizes, int n_in,
                              void* d_out, int out_size, void* d_ws, size_t ws_size,
                              hipStream_t stream) {
    const float* sr = (const float*)d_in[0];
    const float* tm = (const float*)d_in[1];
    const float* w  = (const float*)d_in[2];
    const float* bs = (const float*)d_in[3];
    float* out = (float*)d_out;
    char* wsb = (char*)d_ws;
    __hip_bfloat16* srT = (__hip_bfloat16*)(wsb + OFFB_SRT);
    __hip_bfloat16* tmT = (__hip_bfloat16*)(wsb + OFFB_TMT);
    __hip_bfloat16* wPk = (__hip_bfloat16*)(wsb + OFFB_WPK);
    float* biasP = (float*)(wsb + OFFB_BIAS);
    float* om = (float*)(wsb + OFFB_OM);

    prep<<<2556, 256, 0, stream>>>(sr, tm, w, bs, srT, tmT, wPk, biasP);
    k3_mfma<<<B_ * OH_ * 4, 128, 0, stream>>>(srT, wPk, om);
    k4_gather<<<B_ * OSP, 128, 0, stream>>>(srT, tmT, om, biasP, out);
}

// Round 7
// 139.558 us; speedup vs baseline: 1.0147x; 1.0147x over previous
//
#include <hip/hip_runtime.h>
#include <hip/hip_bf16.h>
#include <math.h>

#define B_ 8
#define C_ 256
#define H_ 31
#define W_ 31
#define T_ 7
#define K_ 49
#define OC_ 147
#define OCP 160
#define OH_ 25
#define OW_ 25
#define NSP 961   // 31*31
#define OSP 625   // 25*25
#define KK_ 2304  // 256*9

typedef __bf16 bf16x8 __attribute__((ext_vector_type(8)));
typedef float f32x4 __attribute__((ext_vector_type(4)));

// workspace layout (byte offsets, all 16B aligned)
#define OFFB_SRT 0                      // 3,936,256  srT bf16 [b][s][c]
#define OFFB_TMT 3936256                // 200,704    tmT bf16 [b][k][c]
#define OFFB_WPK 4136960                // 737,280    wPk bf16 fragment-order (9-shift)
#define OFFB_BIAS 4874240               // 640        biasP f32 [160]
#define OFFB_OM  4874880                // 12,800,000 om f32 [b][i][cg][j=25][oc=160]

__device__ inline float blo(unsigned u) { return __uint_as_float(u << 16); }
__device__ inline float bhi(unsigned u) { return __uint_as_float(u & 0xffff0000u); }

// ---------------- PREP: fused k1 (srT) + k2 (tmT) + k2b (wPk, biasP) ------
// blocks 0..1983: sr transpose; 1984..2375: tmpl transpose; 2376..2555: w pack
__global__ __launch_bounds__(256) void prep(const float* __restrict__ sr,
                                            const float* __restrict__ tm,
                                            const float* __restrict__ w,
                                            const float* __restrict__ bias,
                                            __hip_bfloat16* __restrict__ srT,
                                            __hip_bfloat16* __restrict__ tmT,
                                            __hip_bfloat16* __restrict__ wPk,
                                            float* __restrict__ biasP) {
    __shared__ float tile[32][33];
    int bid = blockIdx.x;
    int t = threadIdx.x;

    if (bid < 1984) {
        // ---- k1: sr (NCHW fp32) -> srT[b][s][c] bf16
        int b = bid / 248;
        int rem = bid % 248;
        int ct = rem / 31;
        int st = rem % 31;
        int c0 = ct * 32, s0 = st * 32;
        int tx = t & 31, ty = t >> 5;
        #pragma unroll
        for (int rr = 0; rr < 4; rr++) {
            int c = c0 + ty + rr * 8;
            int s = s0 + tx;
            if (s < NSP) tile[ty + rr * 8][tx] = sr[(b * C_ + c) * NSP + s];
        }
        __syncthreads();
        #pragma unroll
        for (int rr = 0; rr < 4; rr++) {
            int s = s0 + ty + rr * 8;
            int c = c0 + tx;
            if (s < NSP) srT[((long)b * NSP + s) * C_ + c] = __float2bfloat16(tile[tx][ty + rr * 8]);
        }
    } else if (bid < 2376) {
        // ---- k2: tmpl[b][c][k] -> tmplT[b][k][c] bf16
        int bx = bid - 1984;
        int b = bx / K_;
        int k = bx % K_;
        tmT[(b * K_ + k) * C_ + t] = __float2bfloat16(tm[(b * C_ + t) * K_ + k]);
    } else {
        // ---- k2b: w -> wPk 9-shift fragment order; bias pad
        if (bid == 2376 && t < OCP)
            biasP[t] = (t < OC_) ? bias[t] : 0.f;
        int i = (bid - 2376) * 256 + t;   // 46080 total
        if (i < 46080) {
            int l = i & 63;
            int fid = i >> 6;             // 0..719
            int mf = fid % 5;
            int mh = (fid / 5) % 2;
            int ks = (fid / 10) % 2;
            int s  = (fid / 20) % 9;
            int cg = fid / 180;
            int oc = mh * 80 + mf * 16 + (l & 15);
            int cbase = cg * 64 + ks * 32 + (l >> 4) * 8;
            bf16x8 v;
            #pragma unroll
            for (int jj = 0; jj < 8; jj++) {
                float f = (oc < OC_) ? w[oc * KK_ + (cbase + jj) * 9 + s] : 0.f;
                v[jj] = (__bf16)f;
            }
            *reinterpret_cast<bf16x8*>(wPk + ((long)i << 3)) = v;
        }
    }
}

// ---------------- K3: conv via 9-shift bf16 MFMA GEMM ---------------------
// block = (b, out-row i, channel-group cg); 128 threads = 2 waves (mh 0/1).
// LDS: raw sr slab rows y=i-1..i+1, xi=0..26, 64 ch; row stride 72 bf16 (144B).
// om layout: [b][i][cg][j=25][oc=160] fp32
__global__ __launch_bounds__(128) void k3_mfma(const __hip_bfloat16* __restrict__ srT,
                                               const __hip_bfloat16* __restrict__ wPk,
                                               float* __restrict__ om) {
    __shared__ __hip_bfloat16 lds[88 * 72];   // 81 real rows + margin for j>=25 lanes
    int sb = (blockIdx.x & 7) * 100 + (blockIdx.x >> 3);  // XCD-chunked
    int b = sb / 100;
    int rem = sb % 100;
    int i = rem / 4;
    int cg = rem % 4;
    int tid = threadIdx.x;

    const __hip_bfloat16* srTb = srT + (long)b * NSP * C_ + cg * 64;
    for (int o = tid; o < 648; o += 128) {
        int ryx = o >> 3;
        int c8 = (o & 7) * 8;
        int yy = ryx / 27;
        int xi = ryx - yy * 27;
        int y = i - 1 + yy;
        int x = xi - 1;
        bf16x8 v = {};
        if (y >= 0 && x >= 0)
            v = *reinterpret_cast<const bf16x8*>(srTb + (y * W_ + x) * C_ + c8);
        *reinterpret_cast<bf16x8*>(&lds[ryx * 72 + c8]) = v;
    }
    __syncthreads();

    int wv = tid >> 6;        // mh
    int l = tid & 63;
    int lr = l & 15, lg = l >> 4;

    f32x4 acc[5][2] = {};
    const bf16x8* apk = reinterpret_cast<const bf16x8*>(wPk);

    #pragma unroll
    for (int dy = 0; dy < 3; ++dy) {
        #pragma unroll
        for (int dx = 0; dx < 3; ++dx) {
            int s = dy * 3 + dx;
            #pragma unroll
            for (int ks = 0; ks < 2; ++ks) {
                int e0 = (dy * 27 + dx + lr) * 72 + ks * 32 + lg * 8;
                bf16x8 b0 = *reinterpret_cast<const bf16x8*>(&lds[e0]);
                bf16x8 b1 = *reinterpret_cast<const bf16x8*>(&lds[e0 + 16 * 72]);
                const bf16x8* ap = apk + (long)((((cg * 9 + s) * 2 + ks) * 2 + wv) * 5) * 64 + l;
                #pragma unroll
                for (int mf = 0; mf < 5; ++mf) {
                    bf16x8 a = ap[mf * 64];
                    acc[mf][0] = __builtin_amdgcn_mfma_f32_16x16x32_bf16(a, b0, acc[mf][0], 0, 0, 0);
                    acc[mf][1] = __builtin_amdgcn_mfma_f32_16x16x32_bf16(a, b1, acc[mf][1], 0, 0, 0);
                }
            }
        }
    }

    #pragma unroll
    for (int nf = 0; nf < 2; ++nf) {
        int j = nf * 16 + lr;
        if (j < OW_) {
            float* ob = om + (long)((b * OH_ + i) * 4 + cg) * (OW_ * OCP) + j * OCP + wv * 80 + lg * 4;
            #pragma unroll
            for (int mf = 0; mf < 5; ++mf)
                *reinterpret_cast<f32x4*>(ob + mf * 16) = acc[mf][nf];
        }
    }
}

// ---------------- K4: offsets/mask + bilinear gather + reduce -------------
// block = (b,i,j); ONE 64-lane wave; 4 channels/lane via dwordx2; full 49-k
// loop per wave (long independent load stream = deep MLP); no cross-wave work.
__global__ __launch_bounds__(64) void k4_gather(const __hip_bfloat16* __restrict__ srT,
                                                const __hip_bfloat16* __restrict__ tmT,
                                                const float* __restrict__ om,
                                                const float* __restrict__ biasP,
                                                float* __restrict__ out) {
    __shared__ float lom[OCP];
    __shared__ int4 loff[K_];      // row offsets in uint2 (8B) units
    __shared__ float4 lwt[K_];
    int sb = (blockIdx.x & 7) * 625 + (blockIdx.x >> 3);  // XCD = batch
    int b = sb / OSP;
    int rem = sb % OSP;
    int i = rem / OW_;
    int j = rem % OW_;
    int t = threadIdx.x;

    if (t < 40) {
        f32x4 s = *reinterpret_cast<const f32x4*>(biasP + t * 4);
        const float* ob = om + (long)(b * OH_ + i) * (4 * OW_ * OCP) + j * OCP + t * 4;
        #pragma unroll
        for (int cg = 0; cg < 4; cg++)
            s += *reinterpret_cast<const f32x4*>(ob + cg * (OW_ * OCP));
        *reinterpret_cast<f32x4*>(lom + t * 4) = s;
    }
    __syncthreads();

    if (t < K_) {
        float oy = lom[t];
        float ox = lom[K_ + t];
        float mk = 1.f / (1.f + expf(-lom[2 * K_ + t]));
        float ys = (float)(i + t / T_) + oy;
        float xs = (float)(j + t % T_) + ox;
        float y0f = floorf(ys);
        float x0f = floorf(xs);
        float wy = ys - y0f, wx = xs - x0f;
        bool vy0 = (y0f >= 0.f) && (y0f <= 30.f);
        bool vy1 = (y0f >= -1.f) && (y0f <= 29.f);
        bool vx0 = (x0f >= 0.f) && (x0f <= 30.f);
        bool vx1 = (x0f >= -1.f) && (x0f <= 29.f);
        int iy = (int)y0f;
        int ix = (int)x0f;
        int cy0 = min(max(iy, 0), 30), cy1 = min(max(iy + 1, 0), 30);
        int cx0 = min(max(ix, 0), 30), cx1 = min(max(ix + 1, 0), 30);
        float a00 = (1.f - wy) * (1.f - wx), a01 = (1.f - wy) * wx;
        float a10 = wy * (1.f - wx), a11 = wy * wx;
        lwt[t] = make_float4(mk * a00 * (float)(vy0 && vx0),
                             mk * a01 * (float)(vy0 && vx1),
                             mk * a10 * (float)(vy1 && vx0),
                             mk * a11 * (float)(vy1 && vx1));
        loff[t] = make_int4((cy0 * W_ + cx0) * 64, (cy0 * W_ + cx1) * 64,
                            (cy1 * W_ + cx0) * 64, (cy1 * W_ + cx1) * 64);
    }
    __syncthreads();

    const uint2* srU = reinterpret_cast<const uint2*>(srT) + (long)b * NSP * 64;
    const uint2* tmU = reinterpret_cast<const uint2*>(tmT) + (long)b * K_ * 64;
    float a0 = 0.f, a1 = 0.f, a2 = 0.f, a3 = 0.f;

    for (int k = 0; k < K_; ++k) {
        int4 o = loff[k];
        float4 wt = lwt[k];
        uint2 u00 = srU[o.x + t];
        uint2 u01 = srU[o.y + t];
        uint2 u10 = srU[o.z + t];
        uint2 u11 = srU[o.w + t];
        uint2 tu  = tmU[(k << 6) + t];
        float s;
        s = wt.x * blo(u00.x); s = fmaf(wt.y, blo(u01.x), s);
        s = fmaf(wt.z, blo(u10.x), s); s = fmaf(wt.w, blo(u11.x), s);
        a0 = fmaf(blo(tu.x), s, a0);
        s = wt.x * bhi(u00.x); s = fmaf(wt.y, bhi(u01.x), s);
        s = fmaf(wt.z, bhi(u10.x), s); s = fmaf(wt.w, bhi(u11.x), s);
        a1 = fmaf(bhi(tu.x), s, a1);
        s = wt.x * blo(u00.y); s = fmaf(wt.y, blo(u01.y), s);
        s = fmaf(wt.z, blo(u10.y), s); s = fmaf(wt.w, blo(u11.y), s);
        a2 = fmaf(blo(tu.y), s, a2);
        s = wt.x * bhi(u00.y); s = fmaf(wt.y, bhi(u01.y), s);
        s = fmaf(wt.z, bhi(u10.y), s); s = fmaf(wt.w, bhi(u11.y), s);
        a3 = fmaf(bhi(tu.y), s, a3);
    }

    long ob = ((long)(b * C_ + 4 * t) * OH_ + i) * OW_ + j;
    out[ob] = a0;
    out[ob + OSP] = a1;
    out[ob + 2 * OSP] = a2;
    out[ob + 3 * OSP] = a3;
}

extern "C" void kernel_launch(void* const* d_in, const int* in_sizes, int n_in,
                              void* d_out, int out_size, void* d_ws, size_t ws_size,
                              hipStream_t stream) {
    const float* sr = (const float*)d_in[0];
    const float* tm = (const float*)d_in[1];
    const float* w  = (const float*)d_in[2];
    const float* bs = (const float*)d_in[3];
    float* out = (float*)d_out;
    char* wsb = (char*)d_ws;
    __hip_bfloat16* srT = (__hip_bfloat16*)(wsb + OFFB_SRT);
    __hip_bfloat16* tmT = (__hip_bfloat16*)(wsb + OFFB_TMT);
    __hip_bfloat16* wPk = (__hip_bfloat16*)(wsb + OFFB_WPK);
    float* biasP = (float*)(wsb + OFFB_BIAS);
    float* om = (float*)(wsb + OFFB_OM);

    prep<<<2556, 256, 0, stream>>>(sr, tm, w, bs, srT, tmT, wPk, biasP);
    k3_mfma<<<B_ * OH_ * 4, 128, 0, stream>>>(srT, wPk, om);
    k4_gather<<<B_ * OSP, 64, 0, stream>>>(srT, tmT, om, biasP, out);
}

// Round 8
// 122.948 us; speedup vs baseline: 1.1518x; 1.1351x over previous
//
#include <hip/hip_runtime.h>
#include <hip/hip_bf16.h>
#include <math.h>

#define B_ 8
#define C_ 256
#define H_ 31
#define W_ 31
#define T_ 7
#define K_ 49
#define OC_ 147
#define OCP 160
#define OH_ 25
#define OW_ 25
#define NSP 961   // 31*31
#define OSP 625   // 25*25
#define KK_ 2304  // 256*9

typedef __bf16 bf16x8 __attribute__((ext_vector_type(8)));
typedef float f32x4 __attribute__((ext_vector_type(4)));

// workspace layout (byte offsets, all 16B aligned)
#define OFFB_SRT 0                      // 3,936,256  srT bf16 [b][s][c]
#define OFFB_TMT 3936256                // 200,704    tmT bf16 [b][k][c]
#define OFFB_WPK 4136960                // 737,280    wPk bf16 fragment-order (9-shift)
#define OFFB_BIAS 4874240               // 640        biasP f32 [160]
#define OFFB_OM  4874880                // 12,800,000 om f32 [b][i][cg][j=25][oc=160]

__device__ inline float blo(unsigned u) { return __uint_as_float(u << 16); }
__device__ inline float bhi(unsigned u) { return __uint_as_float(u & 0xffff0000u); }

// ---------------- PREP: fused k1 (srT) + k2 (tmT) + k2b (wPk, biasP) ------
__global__ __launch_bounds__(256) void prep(const float* __restrict__ sr,
                                            const float* __restrict__ tm,
                                            const float* __restrict__ w,
                                            const float* __restrict__ bias,
                                            __hip_bfloat16* __restrict__ srT,
                                            __hip_bfloat16* __restrict__ tmT,
                                            __hip_bfloat16* __restrict__ wPk,
                                            float* __restrict__ biasP) {
    __shared__ float tile[32][33];
    int bid = blockIdx.x;
    int t = threadIdx.x;

    if (bid < 1984) {
        int b = bid / 248;
        int rem = bid % 248;
        int ct = rem / 31;
        int st = rem % 31;
        int c0 = ct * 32, s0 = st * 32;
        int tx = t & 31, ty = t >> 5;
        #pragma unroll
        for (int rr = 0; rr < 4; rr++) {
            int c = c0 + ty + rr * 8;
            int s = s0 + tx;
            if (s < NSP) tile[ty + rr * 8][tx] = sr[(b * C_ + c) * NSP + s];
        }
        __syncthreads();
        #pragma unroll
        for (int rr = 0; rr < 4; rr++) {
            int s = s0 + ty + rr * 8;
            int c = c0 + tx;
            if (s < NSP) srT[((long)b * NSP + s) * C_ + c] = __float2bfloat16(tile[tx][ty + rr * 8]);
        }
    } else if (bid < 2376) {
        int bx = bid - 1984;
        int b = bx / K_;
        int k = bx % K_;
        tmT[(b * K_ + k) * C_ + t] = __float2bfloat16(tm[(b * C_ + t) * K_ + k]);
    } else {
        if (bid == 2376 && t < OCP)
            biasP[t] = (t < OC_) ? bias[t] : 0.f;
        int i = (bid - 2376) * 256 + t;   // 46080 total
        if (i < 46080) {
            int l = i & 63;
            int fid = i >> 6;             // 0..719
            int mf = fid % 5;
            int mh = (fid / 5) % 2;
            int ks = (fid / 10) % 2;
            int s  = (fid / 20) % 9;
            int cg = fid / 180;
            int oc = mh * 80 + mf * 16 + (l & 15);
            int cbase = cg * 64 + ks * 32 + (l >> 4) * 8;
            bf16x8 v;
            #pragma unroll
            for (int jj = 0; jj < 8; jj++) {
                float f = (oc < OC_) ? w[oc * KK_ + (cbase + jj) * 9 + s] : 0.f;
                v[jj] = (__bf16)f;
            }
            *reinterpret_cast<bf16x8*>(wPk + ((long)i << 3)) = v;
        }
    }
}

// ---------------- K3: conv via 9-shift bf16 MFMA GEMM ---------------------
__global__ __launch_bounds__(128) void k3_mfma(const __hip_bfloat16* __restrict__ srT,
                                               const __hip_bfloat16* __restrict__ wPk,
                                               float* __restrict__ om) {
    __shared__ __hip_bfloat16 lds[88 * 72];
    int sb = (blockIdx.x & 7) * 100 + (blockIdx.x >> 3);  // XCD-chunked
    int b = sb / 100;
    int rem = sb % 100;
    int i = rem / 4;
    int cg = rem % 4;
    int tid = threadIdx.x;

    const __hip_bfloat16* srTb = srT + (long)b * NSP * C_ + cg * 64;
    for (int o = tid; o < 648; o += 128) {
        int ryx = o >> 3;
        int c8 = (o & 7) * 8;
        int yy = ryx / 27;
        int xi = ryx - yy * 27;
        int y = i - 1 + yy;
        int x = xi - 1;
        bf16x8 v = {};
        if (y >= 0 && x >= 0)
            v = *reinterpret_cast<const bf16x8*>(srTb + (y * W_ + x) * C_ + c8);
        *reinterpret_cast<bf16x8*>(&lds[ryx * 72 + c8]) = v;
    }
    __syncthreads();

    int wv = tid >> 6;
    int l = tid & 63;
    int lr = l & 15, lg = l >> 4;

    f32x4 acc[5][2] = {};
    const bf16x8* apk = reinterpret_cast<const bf16x8*>(wPk);

    #pragma unroll
    for (int dy = 0; dy < 3; ++dy) {
        #pragma unroll
        for (int dx = 0; dx < 3; ++dx) {
            int s = dy * 3 + dx;
            #pragma unroll
            for (int ks = 0; ks < 2; ++ks) {
                int e0 = (dy * 27 + dx + lr) * 72 + ks * 32 + lg * 8;
                bf16x8 b0 = *reinterpret_cast<const bf16x8*>(&lds[e0]);
                bf16x8 b1 = *reinterpret_cast<const bf16x8*>(&lds[e0 + 16 * 72]);
                const bf16x8* ap = apk + (long)((((cg * 9 + s) * 2 + ks) * 2 + wv) * 5) * 64 + l;
                #pragma unroll
                for (int mf = 0; mf < 5; ++mf) {
                    bf16x8 a = ap[mf * 64];
                    acc[mf][0] = __builtin_amdgcn_mfma_f32_16x16x32_bf16(a, b0, acc[mf][0], 0, 0, 0);
                    acc[mf][1] = __builtin_amdgcn_mfma_f32_16x16x32_bf16(a, b1, acc[mf][1], 0, 0, 0);
                }
            }
        }
    }

    #pragma unroll
    for (int nf = 0; nf < 2; ++nf) {
        int j = nf * 16 + lr;
        if (j < OW_) {
            float* ob = om + (long)((b * OH_ + i) * 4 + cg) * (OW_ * OCP) + j * OCP + wv * 80 + lg * 4;
            #pragma unroll
            for (int mf = 0; mf < 5; ++mf)
                *reinterpret_cast<f32x4*>(ob + mf * 16) = acc[mf][nf];
        }
    }
}

// ---------------- K4: offsets/mask + bilinear gather + reduce -------------
// 256 threads = 4 waves, ONE PIXEL PER WAVE (wave-private LDS slice).
// 2 k's per iteration: lanes 0-31 handle k (8 ch/lane via uint4 = 1KB/instr),
// lanes 32-63 handle k+1. K padded to 50 with zero weights.
// Final: __shfl_xor(32) combine, lanes 0-31 store 8 channels each.
__global__ __launch_bounds__(256) void k4_gather(const __hip_bfloat16* __restrict__ srT,
                                                 const __hip_bfloat16* __restrict__ tmT,
                                                 const float* __restrict__ om,
                                                 const float* __restrict__ biasP,
                                                 float* __restrict__ out) {
    __shared__ float lom[4][OCP];
    __shared__ int4 loff[4][52];      // BYTE row offsets (s*512), [49]=0
    __shared__ float4 lwt[4][52];     // folded weights, [49]=0
    int wvp = threadIdx.x >> 6;
    int l = threadIdx.x & 63;
    // XCD swizzle at block level: 1256 blocks, 1256/8 = 157 exactly
    int blk = (blockIdx.x & 7) * 157 + (blockIdx.x >> 3);
    int pix = blk * 4 + wvp;
    bool active = pix < B_ * OSP;
    int b = 0, i = 0, j = 0;
    if (active) {
        b = pix / OSP;
        int rem = pix % OSP;
        i = rem / OW_;
        j = rem % OW_;
    }

    if (active && l < 40) {
        f32x4 s = *reinterpret_cast<const f32x4*>(biasP + l * 4);
        const float* ob = om + (long)(b * OH_ + i) * (4 * OW_ * OCP) + j * OCP + l * 4;
        #pragma unroll
        for (int cg = 0; cg < 4; cg++)
            s += *reinterpret_cast<const f32x4*>(ob + cg * (OW_ * OCP));
        *reinterpret_cast<f32x4*>(&lom[wvp][l * 4]) = s;
    }
    __syncthreads();

    if (active && l < 50) {
        if (l < K_) {
            float oy = lom[wvp][l];
            float ox = lom[wvp][K_ + l];
            float mk = 1.f / (1.f + expf(-lom[wvp][2 * K_ + l]));
            float ys = (float)(i + l / T_) + oy;
            float xs = (float)(j + l % T_) + ox;
            float y0f = floorf(ys);
            float x0f = floorf(xs);
            float wy = ys - y0f, wx = xs - x0f;
            bool vy0 = (y0f >= 0.f) && (y0f <= 30.f);
            bool vy1 = (y0f >= -1.f) && (y0f <= 29.f);
            bool vx0 = (x0f >= 0.f) && (x0f <= 30.f);
            bool vx1 = (x0f >= -1.f) && (x0f <= 29.f);
            int iy = (int)y0f;
            int ix = (int)x0f;
            int cy0 = min(max(iy, 0), 30), cy1 = min(max(iy + 1, 0), 30);
            int cx0 = min(max(ix, 0), 30), cx1 = min(max(ix + 1, 0), 30);
            float a00 = (1.f - wy) * (1.f - wx), a01 = (1.f - wy) * wx;
            float a10 = wy * (1.f - wx), a11 = wy * wx;
            lwt[wvp][l] = make_float4(mk * a00 * (float)(vy0 && vx0),
                                      mk * a01 * (float)(vy0 && vx1),
                                      mk * a10 * (float)(vy1 && vx0),
                                      mk * a11 * (float)(vy1 && vx1));
            loff[wvp][l] = make_int4((cy0 * W_ + cx0) * 512, (cy0 * W_ + cx1) * 512,
                                     (cy1 * W_ + cx0) * 512, (cy1 * W_ + cx1) * 512);
        } else {
            lwt[wvp][l] = make_float4(0.f, 0.f, 0.f, 0.f);
            loff[wvp][l] = make_int4(0, 0, 0, 0);
        }
    }
    __syncthreads();
    if (!active) return;

    const char* srBase = (const char*)srT + (long)b * NSP * 512;
    const char* tmBase = (const char*)tmT + (long)b * K_ * 512;
    int half = l >> 5;                 // 0: k, 1: k+1
    unsigned laneb = (unsigned)(l & 31) << 4;   // 16B per lane
    float acc[8];
    #pragma unroll
    for (int q = 0; q < 8; q++) acc[q] = 0.f;

    for (int k = 0; k < 50; k += 2) {
        int keff = k + half;
        int4 o = loff[wvp][keff];
        float4 wt = lwt[wvp][keff];
        uint4 u00 = *reinterpret_cast<const uint4*>(srBase + (unsigned)o.x + laneb);
        uint4 u01 = *reinterpret_cast<const uint4*>(srBase + (unsigned)o.y + laneb);
        uint4 u10 = *reinterpret_cast<const uint4*>(srBase + (unsigned)o.z + laneb);
        uint4 u11 = *reinterpret_cast<const uint4*>(srBase + (unsigned)o.w + laneb);
        uint4 tu  = *reinterpret_cast<const uint4*>(tmBase + ((unsigned)keff << 9) + laneb);
        unsigned a_[4] = {u00.x, u00.y, u00.z, u00.w};
        unsigned b_[4] = {u01.x, u01.y, u01.z, u01.w};
        unsigned c_[4] = {u10.x, u10.y, u10.z, u10.w};
        unsigned d_[4] = {u11.x, u11.y, u11.z, u11.w};
        unsigned t_[4] = {tu.x, tu.y, tu.z, tu.w};
        #pragma unroll
        for (int q = 0; q < 4; q++) {
            float s0 = wt.x * blo(a_[q]);
            s0 = fmaf(wt.y, blo(b_[q]), s0);
            s0 = fmaf(wt.z, blo(c_[q]), s0);
            s0 = fmaf(wt.w, blo(d_[q]), s0);
            acc[2 * q] = fmaf(blo(t_[q]), s0, acc[2 * q]);
            float s1 = wt.x * bhi(a_[q]);
            s1 = fmaf(wt.y, bhi(b_[q]), s1);
            s1 = fmaf(wt.z, bhi(c_[q]), s1);
            s1 = fmaf(wt.w, bhi(d_[q]), s1);
            acc[2 * q + 1] = fmaf(bhi(t_[q]), s1, acc[2 * q + 1]);
        }
    }

    #pragma unroll
    for (int q = 0; q < 8; q++) acc[q] += __shfl_xor(acc[q], 32, 64);

    if (l < 32) {
        int c0 = l * 8;
        long ob = ((long)(b * C_ + c0) * OH_ + i) * OW_ + j;
        #pragma unroll
        for (int q = 0; q < 8; q++)
            out[ob + (long)q * OSP] = acc[q];
    }
}

extern "C" void kernel_launch(void* const* d_in, const int* in_sizes, int n_in,
                              void* d_out, int out_size, void* d_ws, size_t ws_size,
                              hipStream_t stream) {
    const float* sr = (const float*)d_in[0];
    const float* tm = (const float*)d_in[1];
    const float* w  = (const float*)d_in[2];
    const float* bs = (const float*)d_in[3];
    float* out = (float*)d_out;
    char* wsb = (char*)d_ws;
    __hip_bfloat16* srT = (__hip_bfloat16*)(wsb + OFFB_SRT);
    __hip_bfloat16* tmT = (__hip_bfloat16*)(wsb + OFFB_TMT);
    __hip_bfloat16* wPk = (__hip_bfloat16*)(wsb + OFFB_WPK);
    float* biasP = (float*)(wsb + OFFB_BIAS);
    float* om = (float*)(wsb + OFFB_OM);

    prep<<<2556, 256, 0, stream>>>(sr, tm, w, bs, srT, tmT, wPk, biasP);
    k3_mfma<<<B_ * OH_ * 4, 128, 0, stream>>>(srT, wPk, om);
    k4_gather<<<1256, 256, 0, stream>>>(srT, tmT, om, biasP, out);
}